// Round 4
// baseline (129.716 us; speedup 1.0000x reference)
//
#include <hip/hip_runtime.h>

#define B_DIM 4096
#define T_DIM 24
#define F_DIM 256
#define O_DIM 24
#define TGT   2

// out[b,o,f] = sum_t x[b,t,f] * W[f,o,t] + bias[f,o],  f in {0,1}
// dtypes (R0-R3 forensics): x (B,T,F) fp32, W (F,O,T) fp32, bias (F,O) fp32,
// out (B,O,TGT) fp32  -- all exactly as the reference declares.
// R2's computation was verified correct; its only bug was a bf16 output store
// into what is an fp32 output buffer.
__global__ __launch_bounds__(256) void DLinear_38268158608117_kernel(
    const float* __restrict__ x,
    const float* __restrict__ W,
    const float* __restrict__ bias,
    float* __restrict__ out)
{
    const int gid = blockIdx.x * blockDim.x + threadIdx.x;   // 0 .. B*O-1 (exact)
    const int b = gid / O_DIM;
    const int o = gid - b * O_DIM;

    // ---- W rows for f=0 and f=1: 24 fp32 = 96 B each, byte offset o*96 (16B-aligned)
    // W[f,o,t] element offset = f*O*T + o*T + t
    const float4* w0p = reinterpret_cast<const float4*>(W + (0 * O_DIM * T_DIM + o * T_DIM));
    const float4* w1p = reinterpret_cast<const float4*>(W + (1 * O_DIM * T_DIM + o * T_DIM));
    float4 w0v[6], w1v[6];
    #pragma unroll
    for (int i = 0; i < 6; ++i) { w0v[i] = w0p[i]; w1v[i] = w1p[i]; }
    const float* w0 = reinterpret_cast<const float*>(w0v);   // 24 fp32
    const float* w1 = reinterpret_cast<const float*>(w1v);

    // ---- x gather: x[b,t,0..1] is one aligned float2
    // float2 index = (b*T*F + t*F)/2 = b*3072 + t*128
    const float2* xp = reinterpret_cast<const float2*>(x);
    const size_t xbase = (size_t)b * (T_DIM * F_DIM / 2);

    float acc0 = 0.f, acc1 = 0.f;
    #pragma unroll
    for (int t = 0; t < T_DIM; ++t) {
        float2 xv = xp[xbase + t * (F_DIM / 2)];
        acc0 = fmaf(xv.x, w0[t], acc0);
        acc1 = fmaf(xv.y, w1[t], acc1);
    }
    acc0 += bias[0 * O_DIM + o];
    acc1 += bias[1 * O_DIM + o];

    // ---- fp32 store: out element index gid*TGT, byte offset gid*8 (8B-aligned)
    float2 r = make_float2(acc0, acc1);
    *reinterpret_cast<float2*>(out + gid * TGT) = r;
}

extern "C" void kernel_launch(void* const* d_in, const int* in_sizes, int n_in,
                              void* d_out, int out_size, void* d_ws, size_t ws_size,
                              hipStream_t stream) {
    const float* x    = (const float*)d_in[0];
    const float* W    = (const float*)d_in[1];
    const float* bias = (const float*)d_in[2];
    float* out = (float*)d_out;

    const int total = B_DIM * O_DIM;                 // 98304 threads
    dim3 block(256);
    dim3 grid(total / 256);                          // 384 blocks, exact
    hipLaunchKernelGGL(DLinear_38268158608117_kernel, grid, block, 0, stream,
                       x, W, bias, out);
}